// Round 1
// baseline (1400.240 us; speedup 1.0000x reference)
//
#include <hip/hip_runtime.h>
#include <cstdint>

typedef unsigned int u32;
typedef unsigned short u16;
typedef __bf16 bf16x8 __attribute__((ext_vector_type(8)));
typedef float f32x4 __attribute__((ext_vector_type(4)));

#define NTOK 4096
#define HDIM 2048
#define FMOE 1024
#define FSH  2048
#define NEXP 16

__device__ __forceinline__ u16 f2bf(float f) {
  u32 u = __float_as_uint(f);
  u32 r = (u + 0x7fffu + ((u >> 16) & 1u)) >> 16;
  return (u16)r;
}
__device__ __forceinline__ float bf2f(u16 h) {
  return __uint_as_float(((u32)h) << 16);
}

__device__ __forceinline__ void gld_lds16(const void* g, void* l) {
  __builtin_amdgcn_global_load_lds(
      (const __attribute__((address_space(1))) u32*)g,
      (__attribute__((address_space(3))) u32*)l, 16, 0, 0);
}

// ---------------- fp32 -> bf16 conversion (vectorized x4) ----------------
__global__ void cvt_bf16(const float* __restrict__ in, u16* __restrict__ out, long n4) {
  long i = (long)blockIdx.x * blockDim.x + threadIdx.x;
  if (i < n4) {
    float4 v = ((const float4*)in)[i];
    ushort4 o;
    o.x = f2bf(v.x); o.y = f2bf(v.y); o.z = f2bf(v.z); o.w = f2bf(v.w);
    ((ushort4*)out)[i] = o;
  }
}

// ---------------- routing: one wave per token ----------------
__global__ void routing_kernel(const float* __restrict__ hidden,
                               const float* __restrict__ gw,
                               const float* __restrict__ bias,
                               int* __restrict__ topk_idx,
                               float* __restrict__ topk_w,
                               int* __restrict__ counts) {
  int t = blockIdx.x * 4 + (threadIdx.x >> 6);
  int lane = threadIdx.x & 63;
  const float* h = hidden + (long)t * HDIM;
  float acc[NEXP];
#pragma unroll
  for (int n = 0; n < NEXP; ++n) acc[n] = 0.f;
  for (int i = lane; i < HDIM; i += 64) {
    float hv = h[i];
#pragma unroll
    for (int n = 0; n < NEXP; ++n) acc[n] += hv * gw[n * HDIM + i];
  }
#pragma unroll
  for (int n = 0; n < NEXP; ++n) {
    float v = acc[n];
    for (int m = 32; m; m >>= 1) v += __shfl_xor(v, m);
    acc[n] = v;
  }
  if (lane == 0) {
    float sc[NEXP], scb[NEXP];
#pragma unroll
    for (int n = 0; n < NEXP; ++n) {
      sc[n] = 1.f / (1.f + expf(-acc[n]));
      scb[n] = sc[n] + bias[n];
    }
    // group scores: sum of top-2 within each group of 4
    float gs[4];
#pragma unroll
    for (int g = 0; g < 4; ++g) {
      float m1 = -1e30f, m2 = -1e30f;
#pragma unroll
      for (int j = 0; j < 4; ++j) {
        float v = scb[4 * g + j];
        if (v > m1) { m2 = m1; m1 = v; } else if (v > m2) { m2 = v; }
      }
      gs[g] = m1 + m2;
    }
    // top-2 groups (first-occurrence argmax, matching jax top_k tie rules)
    int g1 = -1, g2 = -1;
    { float b = -1e30f; for (int g = 0; g < 4; ++g) if (gs[g] > b) { b = gs[g]; g1 = g; } }
    { float b = -1e30f; for (int g = 0; g < 4; ++g) if (g != g1 && gs[g] > b) { b = gs[g]; g2 = g; } }
    bool used[NEXP];
#pragma unroll
    for (int n = 0; n < NEXP; ++n) used[n] = false;
    int sel[4]; float wts[4]; float s = 0.f;
    for (int k = 0; k < 4; ++k) {
      float b = -1e30f; int bi = 0;
      for (int n = 0; n < NEXP; ++n) {
        int g = n >> 2;
        if ((g == g1 || g == g2) && !used[n] && scb[n] > b) { b = scb[n]; bi = n; }
      }
      used[bi] = true; sel[k] = bi; wts[k] = sc[bi]; s += sc[bi];
    }
    float inv = 2.5f / (s + 1e-20f);
    for (int k = 0; k < 4; ++k) {
      topk_idx[t * 4 + k] = sel[k];
      topk_w[t * 4 + k] = wts[k] * inv;
      atomicAdd(&counts[sel[k]], 1);
    }
  }
}

// ---------------- prefix over 16 counts ----------------
__global__ void prefix16(const int* __restrict__ counts, int* __restrict__ offs) {
  if (threadIdx.x == 0) {
    int s = 0;
    for (int e = 0; e < NEXP; ++e) { offs[e] = s; s += counts[e]; }
    offs[NEXP] = s;
  }
}

// ---------------- deterministic ordered compaction, one block per expert ----------------
__global__ void fill_lists(const int* __restrict__ topk_idx, const float* __restrict__ topk_w,
                           const int* __restrict__ offs, int* __restrict__ ltok,
                           float* __restrict__ lwgt) {
  int e = blockIdx.x;
  int tid = threadIdx.x, lane = tid & 63, wv = tid >> 6;
  __shared__ int cursor;
  __shared__ int wcnt[4];
  if (tid == 0) cursor = offs[e];
  __syncthreads();
  for (int base = 0; base < NTOK; base += 256) {
    int t = base + tid;
    int flag = 0; float w = 0.f;
#pragma unroll
    for (int k = 0; k < 4; ++k) {
      if (topk_idx[t * 4 + k] == e) { flag = 1; w = topk_w[t * 4 + k]; }
    }
    unsigned long long b = __ballot(flag);
    if (lane == 0) wcnt[wv] = __popcll(b);
    __syncthreads();
    int pre = 0;
    for (int i = 0; i < wv; ++i) pre += wcnt[i];
    int pos = cursor + pre + __popcll(b & ((1ull << lane) - 1ull));
    if (flag) { ltok[pos] = t; lwgt[pos] = w; }
    __syncthreads();
    if (tid == 0) cursor += wcnt[0] + wcnt[1] + wcnt[2] + wcnt[3];
    __syncthreads();
  }
}

// ---------------- act = silu(g) * u, bf16 in/out, optional dynamic row count ----------------
__global__ void silu_mul_kernel(const u16* __restrict__ g, const u16* __restrict__ u,
                                u16* __restrict__ act, const int* __restrict__ nrows_ptr,
                                int nrows_static, int F) {
  int rows = nrows_ptr ? *nrows_ptr : nrows_static;
  long total4 = (long)rows * F / 4;
  long i = (long)blockIdx.x * blockDim.x + threadIdx.x;
  if (i < total4) {
    ushort4 gv = ((const ushort4*)g)[i];
    ushort4 uv = ((const ushort4*)u)[i];
    float gf, uf, sv;
    ushort4 o;
    gf = bf2f(gv.x); uf = bf2f(uv.x); sv = gf / (1.f + __expf(-gf)); o.x = f2bf(sv * uf);
    gf = bf2f(gv.y); uf = bf2f(uv.y); sv = gf / (1.f + __expf(-gf)); o.y = f2bf(sv * uf);
    gf = bf2f(gv.z); uf = bf2f(uv.z); sv = gf / (1.f + __expf(-gf)); o.z = f2bf(sv * uf);
    gf = bf2f(gv.w); uf = bf2f(uv.w); sv = gf / (1.f + __expf(-gf)); o.w = f2bf(sv * uf);
    ((ushort4*)act)[i] = o;
  }
}

// ---------------- 128x128 bf16 GEMM-BT (C = A @ B^T), m97-style ----------------
// EPI 0: store bf16 to Cb[(seg0+row)*N + col]
// EPI 1: store f32  to Cf[row*N + col]
// EPI 2: atomicAdd  Cf[tok[row]*N + col] += wgt[row] * val
template <int EPI>
__global__ __launch_bounds__(256) void gemm_bt(
    const u16* __restrict__ A, const u16* __restrict__ B,
    u16* __restrict__ Cb, float* __restrict__ Cf,
    const int* __restrict__ gather, const int* __restrict__ tok,
    const float* __restrict__ wgt, const int* __restrict__ offs,
    int Mstatic, int N, int K, long Bstride) {
  int e = blockIdx.z;
  int seg0 = 0, segM = Mstatic;
  if (offs) { seg0 = offs[e]; segM = offs[e + 1] - seg0; }
  int mt = blockIdx.y, nt = blockIdx.x;
  if (mt * 128 >= segM) return;
  const u16* Be = B + (long)e * Bstride;

  __shared__ __align__(16) u16 As[128 * 64];
  __shared__ __align__(16) u16 Bs[128 * 64];

  int tid = threadIdx.x;
  int lane = tid & 63;
  int wv = tid >> 6;
  int wm = (wv >> 1) * 64, wn = (wv & 1) * 64;
  int c4 = lane & 15, r4 = lane >> 4;

  // staging addresses: thread covers rows (tid>>3)+i*32, 8 lanes * 16B per row of BK=64 bf16
  const u16* arow[4];
  const u16* brow[4];
  int ldsoff = ((tid >> 3) * 64) + (tid & 7) * 8;
#pragma unroll
  for (int i = 0; i < 4; ++i) {
    int r = (tid >> 3) + i * 32;
    int rl = mt * 128 + r;
    if (rl >= segM) rl = mt * 128;  // clamp to a valid row (masked at store)
    int ridx = seg0 + rl;
    long arowidx = gather ? (long)gather[ridx] : (long)ridx;
    arow[i] = A + arowidx * K + (tid & 7) * 8;
    brow[i] = Be + (long)(nt * 128 + r) * K + (tid & 7) * 8;
  }

  f32x4 acc[4][4];
#pragma unroll
  for (int i = 0; i < 4; ++i)
#pragma unroll
    for (int j = 0; j < 4; ++j) acc[i][j] = f32x4{0.f, 0.f, 0.f, 0.f};

  int nkt = K >> 6;
  for (int kt = 0; kt < nkt; ++kt) {
    __syncthreads();
#pragma unroll
    for (int i = 0; i < 4; ++i) {
      gld_lds16(arow[i] + kt * 64, &As[ldsoff + i * 2048]);
      gld_lds16(brow[i] + kt * 64, &Bs[ldsoff + i * 2048]);
    }
    __syncthreads();
#pragma unroll
    for (int kk = 0; kk < 2; ++kk) {
      int ko = kk * 32 + r4 * 8;
      bf16x8 af[4], bfr[4];
#pragma unroll
      for (int mi = 0; mi < 4; ++mi)
        af[mi] = *(const bf16x8*)&As[(wm + mi * 16 + c4) * 64 + ko];
#pragma unroll
      for (int ni = 0; ni < 4; ++ni)
        bfr[ni] = *(const bf16x8*)&Bs[(wn + ni * 16 + c4) * 64 + ko];
#pragma unroll
      for (int mi = 0; mi < 4; ++mi)
#pragma unroll
        for (int ni = 0; ni < 4; ++ni)
          acc[mi][ni] = __builtin_amdgcn_mfma_f32_16x16x32_bf16(af[mi], bfr[ni], acc[mi][ni], 0, 0, 0);
    }
  }

  if (EPI == 2) {
    __syncthreads();
    int* stok = (int*)As;
    float* sw = (float*)Bs;
    if (tid < 128) {
      int lr = mt * 128 + tid;
      bool v = lr < segM;
      stok[tid] = v ? tok[seg0 + lr] : 0;
      sw[tid] = v ? wgt[seg0 + lr] : 0.f;
    }
    __syncthreads();
#pragma unroll
    for (int mi = 0; mi < 4; ++mi)
#pragma unroll
      for (int r = 0; r < 4; ++r) {
        int lr = wm + mi * 16 + r4 * 4 + r;
        if (mt * 128 + lr < segM) {
          int t = stok[lr];
          float w = sw[lr];
          long base = (long)t * N + nt * 128 + wn + c4;
#pragma unroll
          for (int ni = 0; ni < 4; ++ni)
            atomicAdd(&Cf[base + ni * 16], w * acc[mi][ni][r]);
        }
      }
  } else {
#pragma unroll
    for (int mi = 0; mi < 4; ++mi)
#pragma unroll
      for (int r = 0; r < 4; ++r) {
        int lr = wm + mi * 16 + r4 * 4 + r;
        if (mt * 128 + lr < segM) {
          long base = (long)(seg0 + mt * 128 + lr) * N + nt * 128 + wn + c4;
          if (EPI == 0) {
#pragma unroll
            for (int ni = 0; ni < 4; ++ni) Cb[base + ni * 16] = f2bf(acc[mi][ni][r]);
          } else {
#pragma unroll
            for (int ni = 0; ni < 4; ++ni) Cf[base + ni * 16] = acc[mi][ni][r];
          }
        }
      }
  }
}

extern "C" void kernel_launch(void* const* d_in, const int* in_sizes, int n_in,
                              void* d_out, int out_size, void* d_ws, size_t ws_size,
                              hipStream_t stream) {
  const float* hidden = (const float*)d_in[0];       // [4096, 2048]
  const float* gate_weight = (const float*)d_in[1];  // [16, 2048]
  const float* bias = (const float*)d_in[2];         // [16]
  const float* gate_w = (const float*)d_in[3];       // [16, 1024, 2048]
  const float* up_w = (const float*)d_in[4];         // [16, 1024, 2048]
  const float* down_w = (const float*)d_in[5];       // [16, 2048, 1024]
  const float* shg = (const float*)d_in[6];          // [2048, 2048]
  const float* shu = (const float*)d_in[7];          // [2048, 2048]
  const float* shd = (const float*)d_in[8];          // [2048, 2048]
  float* out = (float*)d_out;                        // [4096, 2048]

  char* p = (char*)d_ws;
  auto alloc = [&](size_t bytes) {
    char* q = p;
    p += (bytes + 255) & ~(size_t)255;
    return q;
  };
  u16* Xb = (u16*)alloc((size_t)NTOK * HDIM * 2);           // bf16 hidden
  u16* Gb = (u16*)alloc((size_t)NEXP * FMOE * HDIM * 2);    // bf16 gate_w
  u16* Ub = (u16*)alloc((size_t)NEXP * FMOE * HDIM * 2);    // bf16 up_w
  u16* Db = (u16*)alloc((size_t)NEXP * HDIM * FMOE * 2);    // bf16 down_w
  u16* SGb = (u16*)alloc((size_t)FSH * HDIM * 2);
  u16* SUb = (u16*)alloc((size_t)FSH * HDIM * 2);
  u16* SDb = (u16*)alloc((size_t)HDIM * FSH * 2);
  u16* gbuf = (u16*)alloc((size_t)NTOK * 4 * FMOE * 2);     // routed gate / act (in-place)
  u16* ubuf = (u16*)alloc((size_t)NTOK * 4 * FMOE * 2);     // routed up
  u16* gsbuf = (u16*)alloc((size_t)NTOK * FSH * 2);         // shared gate / act
  u16* usbuf = (u16*)alloc((size_t)NTOK * FSH * 2);         // shared up
  int* topki = (int*)alloc((size_t)NTOK * 4 * 4);
  float* topkw = (float*)alloc((size_t)NTOK * 4 * 4);
  int* counts = (int*)alloc(64);
  int* offs = (int*)alloc(128);
  int* ltok = (int*)alloc((size_t)NTOK * 4 * 4);
  float* lwgt = (float*)alloc((size_t)NTOK * 4 * 4);

  // fp32 -> bf16 conversions
  cvt_bf16<<<8192, 256, 0, stream>>>(hidden, Xb, (long)NTOK * HDIM / 4);
  cvt_bf16<<<32768, 256, 0, stream>>>(gate_w, Gb, (long)NEXP * FMOE * HDIM / 4);
  cvt_bf16<<<32768, 256, 0, stream>>>(up_w, Ub, (long)NEXP * FMOE * HDIM / 4);
  cvt_bf16<<<32768, 256, 0, stream>>>(down_w, Db, (long)NEXP * HDIM * FMOE / 4);
  cvt_bf16<<<4096, 256, 0, stream>>>(shg, SGb, (long)FSH * HDIM / 4);
  cvt_bf16<<<4096, 256, 0, stream>>>(shu, SUb, (long)FSH * HDIM / 4);
  cvt_bf16<<<4096, 256, 0, stream>>>(shd, SDb, (long)HDIM * FSH / 4);

  // routing + expert lists
  hipMemsetAsync(counts, 0, 64, stream);
  routing_kernel<<<NTOK / 4, 256, 0, stream>>>(hidden, gate_weight, bias, topki, topkw, counts);
  prefix16<<<1, 64, 0, stream>>>(counts, offs);
  fill_lists<<<NEXP, 256, 0, stream>>>(topki, topkw, offs, ltok, lwgt);

  // routed gate / up GEMMs (gathered rows of Xb), then act
  gemm_bt<0><<<dim3(FMOE / 128, 32, NEXP), 256, 0, stream>>>(
      Xb, Gb, gbuf, nullptr, ltok, nullptr, nullptr, offs, 0, FMOE, HDIM, (long)FMOE * HDIM);
  gemm_bt<0><<<dim3(FMOE / 128, 32, NEXP), 256, 0, stream>>>(
      Xb, Ub, ubuf, nullptr, ltok, nullptr, nullptr, offs, 0, FMOE, HDIM, (long)FMOE * HDIM);
  silu_mul_kernel<<<16384, 256, 0, stream>>>(gbuf, ubuf, gbuf, offs + NEXP, 0, FMOE);

  // shared expert
  gemm_bt<0><<<dim3(FSH / 128, 32, 1), 256, 0, stream>>>(
      Xb, SGb, gsbuf, nullptr, nullptr, nullptr, nullptr, nullptr, NTOK, FSH, HDIM, 0);
  gemm_bt<0><<<dim3(FSH / 128, 32, 1), 256, 0, stream>>>(
      Xb, SUb, usbuf, nullptr, nullptr, nullptr, nullptr, nullptr, NTOK, FSH, HDIM, 0);
  silu_mul_kernel<<<8192, 256, 0, stream>>>(gsbuf, usbuf, gsbuf, nullptr, NTOK, FSH);
  // shared down: plain f32 store initializes out
  gemm_bt<1><<<dim3(HDIM / 128, 32, 1), 256, 0, stream>>>(
      gsbuf, SDb, nullptr, out, nullptr, nullptr, nullptr, nullptr, NTOK, HDIM, FSH, 0);
  // routed down: weighted atomic scatter-add into out
  gemm_bt<2><<<dim3(HDIM / 128, 32, NEXP), 256, 0, stream>>>(
      gbuf, Db, nullptr, out, nullptr, ltok, lwgt, offs, 0, HDIM, FMOE, (long)HDIM * FMOE);
}

// Round 2
// 1300.728 us; speedup vs baseline: 1.0765x; 1.0765x over previous
//
#include <hip/hip_runtime.h>
#include <cstdint>

typedef unsigned int u32;
typedef unsigned short u16;
typedef __bf16 bf16x8 __attribute__((ext_vector_type(8)));
typedef float f32x4 __attribute__((ext_vector_type(4)));

#define NTOK 4096
#define HDIM 2048
#define FMOE 1024
#define FSH  2048
#define NEXP 16

__device__ __forceinline__ u16 f2bf(float f) {
  u32 u = __float_as_uint(f);
  u32 r = (u + 0x7fffu + ((u >> 16) & 1u)) >> 16;
  return (u16)r;
}
__device__ __forceinline__ float bf2f(u16 h) {
  return __uint_as_float(((u32)h) << 16);
}

__device__ __forceinline__ void gld_lds16(const void* g, void* l) {
  __builtin_amdgcn_global_load_lds(
      (const __attribute__((address_space(1))) u32*)g,
      (__attribute__((address_space(3))) u32*)l, 16, 0, 0);
}

// ---------------- fp32 -> bf16 conversion (vectorized x4) ----------------
__global__ void cvt_bf16(const float* __restrict__ in, u16* __restrict__ out, long n4) {
  long i = (long)blockIdx.x * blockDim.x + threadIdx.x;
  if (i < n4) {
    float4 v = ((const float4*)in)[i];
    ushort4 o;
    o.x = f2bf(v.x); o.y = f2bf(v.y); o.z = f2bf(v.z); o.w = f2bf(v.w);
    ((ushort4*)out)[i] = o;
  }
}

// convert gate_w + up_w into concatenated per-expert layout GU[e][0:F]=gate, GU[e][F:2F]=up
__global__ void cvt_pair_moe(const float* __restrict__ g, const float* __restrict__ u,
                             u16* __restrict__ dst) {
  int e = blockIdx.z;
  const long n4 = (long)FMOE * HDIM / 4;
  long i = (long)blockIdx.x * blockDim.x + threadIdx.x;
  const float4* gs = (const float4*)(g + (long)e * FMOE * HDIM);
  const float4* us = (const float4*)(u + (long)e * FMOE * HDIM);
  ushort4* d = (ushort4*)(dst + (long)e * 2 * FMOE * HDIM);
  float4 v = gs[i];
  ushort4 o;
  o.x = f2bf(v.x); o.y = f2bf(v.y); o.z = f2bf(v.z); o.w = f2bf(v.w);
  d[i] = o;
  v = us[i];
  o.x = f2bf(v.x); o.y = f2bf(v.y); o.z = f2bf(v.z); o.w = f2bf(v.w);
  d[n4 + i] = o;
}

// ---------------- routing: gate weights staged in LDS, one wave per token ----------------
__global__ __launch_bounds__(256) void routing_kernel(
    const float* __restrict__ hidden, const float* __restrict__ gw,
    const float* __restrict__ bias, int* __restrict__ topk_idx,
    float* __restrict__ topk_w, int* __restrict__ counts) {
  __shared__ float gws[8 * HDIM];  // 64 KB: 8 experts per pass
  int tid = threadIdx.x, lane = tid & 63, wv = tid >> 6;
  int t = blockIdx.x * 4 + wv;
  float acc[NEXP];
#pragma unroll
  for (int n = 0; n < NEXP; ++n) acc[n] = 0.f;
  const float4* h4 = (const float4*)(hidden + (long)t * HDIM);

  for (int half = 0; half < 2; ++half) {
    for (int i = tid; i < 8 * HDIM / 4; i += 256)
      ((float4*)gws)[i] = ((const float4*)(gw + half * 8 * HDIM))[i];
    __syncthreads();
#pragma unroll
    for (int j0 = 0; j0 < HDIM / 4; j0 += 64) {
      int j = j0 + lane;
      float4 hv = h4[j];
#pragma unroll
      for (int e = 0; e < 8; ++e) {
        float4 g = ((const float4*)gws)[e * (HDIM / 4) + j];
        acc[half * 8 + e] += hv.x * g.x + hv.y * g.y + hv.z * g.z + hv.w * g.w;
      }
    }
    __syncthreads();
  }
#pragma unroll
  for (int n = 0; n < NEXP; ++n) {
    float v = acc[n];
    for (int m = 32; m; m >>= 1) v += __shfl_xor(v, m);
    acc[n] = v;
  }
  if (lane == 0) {
    float sc[NEXP], scb[NEXP];
#pragma unroll
    for (int n = 0; n < NEXP; ++n) {
      sc[n] = 1.f / (1.f + expf(-acc[n]));
      scb[n] = sc[n] + bias[n];
    }
    float gs[4];
#pragma unroll
    for (int g = 0; g < 4; ++g) {
      float m1 = -1e30f, m2 = -1e30f;
#pragma unroll
      for (int j = 0; j < 4; ++j) {
        float v = scb[4 * g + j];
        if (v > m1) { m2 = m1; m1 = v; } else if (v > m2) { m2 = v; }
      }
      gs[g] = m1 + m2;
    }
    int g1 = -1, g2 = -1;
    { float b = -1e30f; for (int g = 0; g < 4; ++g) if (gs[g] > b) { b = gs[g]; g1 = g; } }
    { float b = -1e30f; for (int g = 0; g < 4; ++g) if (g != g1 && gs[g] > b) { b = gs[g]; g2 = g; } }
    bool used[NEXP];
#pragma unroll
    for (int n = 0; n < NEXP; ++n) used[n] = false;
    int sel[4]; float wts[4]; float s = 0.f;
    for (int k = 0; k < 4; ++k) {
      float b = -1e30f; int bi = 0;
      for (int n = 0; n < NEXP; ++n) {
        int g = n >> 2;
        if ((g == g1 || g == g2) && !used[n] && scb[n] > b) { b = scb[n]; bi = n; }
      }
      used[bi] = true; sel[k] = bi; wts[k] = sc[bi]; s += sc[bi];
    }
    float inv = 2.5f / (s + 1e-20f);
    for (int k = 0; k < 4; ++k) {
      topk_idx[t * 4 + k] = sel[k];
      topk_w[t * 4 + k] = wts[k] * inv;
      atomicAdd(&counts[sel[k]], 1);
    }
  }
}

// ---------------- prefix over 16 counts ----------------
__global__ void prefix16(const int* __restrict__ counts, int* __restrict__ offs) {
  if (threadIdx.x == 0) {
    int s = 0;
    for (int e = 0; e < NEXP; ++e) { offs[e] = s; s += counts[e]; }
    offs[NEXP] = s;
  }
}

// ---------------- deterministic ordered compaction + slot map ----------------
__global__ void fill_lists(const int* __restrict__ topk_idx,
                           const int* __restrict__ offs, int* __restrict__ ltok,
                           int* __restrict__ slotmap) {
  int e = blockIdx.x;
  int tid = threadIdx.x, lane = tid & 63, wv = tid >> 6;
  __shared__ int cursor;
  __shared__ int wcnt[4];
  if (tid == 0) cursor = offs[e];
  __syncthreads();
  for (int base = 0; base < NTOK; base += 256) {
    int t = base + tid;
    int flag = 0, kk = 0;
#pragma unroll
    for (int k = 0; k < 4; ++k) {
      if (topk_idx[t * 4 + k] == e) { flag = 1; kk = k; }
    }
    unsigned long long b = __ballot(flag);
    if (lane == 0) wcnt[wv] = __popcll(b);
    __syncthreads();
    int pre = 0;
    for (int i = 0; i < wv; ++i) pre += wcnt[i];
    int pos = cursor + pre + __popcll(b & ((1ull << lane) - 1ull));
    if (flag) { ltok[pos] = t; slotmap[t * 4 + kk] = pos; }
    __syncthreads();
    if (tid == 0) cursor += wcnt[0] + wcnt[1] + wcnt[2] + wcnt[3];
    __syncthreads();
  }
}

// ---------------- in-place paired silu: gu[row][f] = silu(gu[row][f]) * gu[row][F+f] ----------------
template <int F>
__global__ void silu_mul_pair(u16* __restrict__ gu, const int* __restrict__ nrows_ptr,
                              int nrows_static) {
  int rows = nrows_ptr ? *nrows_ptr : nrows_static;
  long total4 = (long)rows * (F / 4);
  long i = (long)blockIdx.x * blockDim.x + threadIdx.x;
  if (i < total4) {
    long row = i / (F / 4);
    int f4 = (int)(i - row * (F / 4));
    ushort4* rowp = (ushort4*)(gu + row * 2 * F);
    ushort4 gv = rowp[f4];
    ushort4 uv = rowp[F / 4 + f4];
    float gf, uf, sv;
    ushort4 o;
    gf = bf2f(gv.x); uf = bf2f(uv.x); sv = gf / (1.f + __expf(-gf)); o.x = f2bf(sv * uf);
    gf = bf2f(gv.y); uf = bf2f(uv.y); sv = gf / (1.f + __expf(-gf)); o.y = f2bf(sv * uf);
    gf = bf2f(gv.z); uf = bf2f(uv.z); sv = gf / (1.f + __expf(-gf)); o.z = f2bf(sv * uf);
    gf = bf2f(gv.w); uf = bf2f(uv.w); sv = gf / (1.f + __expf(-gf)); o.w = f2bf(sv * uf);
    rowp[f4] = o;
  }
}

// ---------------- final reduce: out[t] = SY[t] + sum_k w[t,k] * Y[slot(t,k)] ----------------
__global__ void reduce_out(const u16* __restrict__ SY, const u16* __restrict__ Y,
                           const int* __restrict__ slotmap, const float* __restrict__ tkw,
                           float* __restrict__ out) {
  long i = (long)blockIdx.x * blockDim.x + threadIdx.x;  // over NTOK*HDIM/4
  int t = (int)(i >> 9);       // HDIM/4 = 512
  int c4 = (int)(i & 511);
  ushort4 s = ((const ushort4*)SY)[i];
  float4 o;
  o.x = bf2f(s.x); o.y = bf2f(s.y); o.z = bf2f(s.z); o.w = bf2f(s.w);
#pragma unroll
  for (int k = 0; k < 4; ++k) {
    int sl = slotmap[t * 4 + k];
    float w = tkw[t * 4 + k];
    ushort4 y = ((const ushort4*)Y)[(long)sl * 512 + c4];
    o.x += w * bf2f(y.x);
    o.y += w * bf2f(y.y);
    o.z += w * bf2f(y.z);
    o.w += w * bf2f(y.w);
  }
  ((float4*)out)[i] = o;
}

// ---------------- 128x128 bf16 GEMM-BT (C = A @ B^T), m97-style, bf16 store ----------------
__global__ __launch_bounds__(256) void gemm_bt(
    const u16* __restrict__ A, const u16* __restrict__ B, u16* __restrict__ C,
    const int* __restrict__ gather, const int* __restrict__ offs,
    int Mstatic, int N, int K, int lda, long Bstride) {
  int e = blockIdx.z;
  int seg0 = 0, segM = Mstatic;
  if (offs) { seg0 = offs[e]; segM = offs[e + 1] - seg0; }
  int mt = blockIdx.y, nt = blockIdx.x;
  if (mt * 128 >= segM) return;
  const u16* Be = B + (long)e * Bstride;

  __shared__ __align__(16) u16 As[128 * 64];
  __shared__ __align__(16) u16 Bs[128 * 64];

  int tid = threadIdx.x;
  int lane = tid & 63;
  int wv = tid >> 6;
  int wm = (wv >> 1) * 64, wn = (wv & 1) * 64;
  int c4 = lane & 15, r4 = lane >> 4;

  const u16* arow[4];
  const u16* brow[4];
  int ldsoff = ((tid >> 3) * 64) + (tid & 7) * 8;
#pragma unroll
  for (int i = 0; i < 4; ++i) {
    int r = (tid >> 3) + i * 32;
    int rl = mt * 128 + r;
    if (rl >= segM) rl = mt * 128;  // clamp to valid row (masked at store)
    int ridx = seg0 + rl;
    long arowidx = gather ? (long)gather[ridx] : (long)ridx;
    arow[i] = A + arowidx * lda + (tid & 7) * 8;
    brow[i] = Be + (long)(nt * 128 + r) * K + (tid & 7) * 8;
  }

  f32x4 acc[4][4];
#pragma unroll
  for (int i = 0; i < 4; ++i)
#pragma unroll
    for (int j = 0; j < 4; ++j) acc[i][j] = f32x4{0.f, 0.f, 0.f, 0.f};

  int nkt = K >> 6;
  for (int kt = 0; kt < nkt; ++kt) {
    __syncthreads();
#pragma unroll
    for (int i = 0; i < 4; ++i) {
      gld_lds16(arow[i] + kt * 64, &As[ldsoff + i * 2048]);
      gld_lds16(brow[i] + kt * 64, &Bs[ldsoff + i * 2048]);
    }
    __syncthreads();
#pragma unroll
    for (int kk = 0; kk < 2; ++kk) {
      int ko = kk * 32 + r4 * 8;
      bf16x8 af[4], bfr[4];
#pragma unroll
      for (int mi = 0; mi < 4; ++mi)
        af[mi] = *(const bf16x8*)&As[(wm + mi * 16 + c4) * 64 + ko];
#pragma unroll
      for (int ni = 0; ni < 4; ++ni)
        bfr[ni] = *(const bf16x8*)&Bs[(wn + ni * 16 + c4) * 64 + ko];
#pragma unroll
      for (int mi = 0; mi < 4; ++mi)
#pragma unroll
        for (int ni = 0; ni < 4; ++ni)
          acc[mi][ni] = __builtin_amdgcn_mfma_f32_16x16x32_bf16(af[mi], bfr[ni], acc[mi][ni], 0, 0, 0);
    }
  }

#pragma unroll
  for (int mi = 0; mi < 4; ++mi)
#pragma unroll
    for (int r = 0; r < 4; ++r) {
      int lr = wm + mi * 16 + r4 * 4 + r;
      if (mt * 128 + lr < segM) {
        long base = (long)(seg0 + mt * 128 + lr) * N + nt * 128 + wn + c4;
#pragma unroll
        for (int ni = 0; ni < 4; ++ni) C[base + ni * 16] = f2bf(acc[mi][ni][r]);
      }
    }
}

extern "C" void kernel_launch(void* const* d_in, const int* in_sizes, int n_in,
                              void* d_out, int out_size, void* d_ws, size_t ws_size,
                              hipStream_t stream) {
  const float* hidden = (const float*)d_in[0];       // [4096, 2048]
  const float* gate_weight = (const float*)d_in[1];  // [16, 2048]
  const float* bias = (const float*)d_in[2];         // [16]
  const float* gate_w = (const float*)d_in[3];       // [16, 1024, 2048]
  const float* up_w = (const float*)d_in[4];         // [16, 1024, 2048]
  const float* down_w = (const float*)d_in[5];       // [16, 2048, 1024]
  const float* shg = (const float*)d_in[6];          // [2048, 2048]
  const float* shu = (const float*)d_in[7];          // [2048, 2048]
  const float* shd = (const float*)d_in[8];          // [2048, 2048]
  float* out = (float*)d_out;                        // [4096, 2048]

  char* p = (char*)d_ws;
  auto alloc = [&](size_t bytes) {
    char* q = p;
    p += (bytes + 255) & ~(size_t)255;
    return q;
  };
  u16* Xb = (u16*)alloc((size_t)NTOK * HDIM * 2);                 // 16 MB bf16 hidden
  u16* GUb = (u16*)alloc((size_t)NEXP * 2 * FMOE * HDIM * 2);     // 128 MB [e][gate;up]
  u16* Db = (u16*)alloc((size_t)NEXP * HDIM * FMOE * 2);          // 64 MB
  u16* SGUb = (u16*)alloc((size_t)2 * FSH * HDIM * 2);            // 16 MB [gate;up]
  u16* SDb = (u16*)alloc((size_t)HDIM * FSH * 2);                 // 8 MB
  u16* gu_out = (u16*)alloc((size_t)NTOK * 4 * 2 * FMOE * 2);     // 64 MB routed gate|up, act in-place
  int* topki = (int*)alloc((size_t)NTOK * 4 * 4);
  float* topkw = (float*)alloc((size_t)NTOK * 4 * 4);
  int* counts = (int*)alloc(64);
  int* offs = (int*)alloc(128);
  int* ltok = (int*)alloc((size_t)NTOK * 4 * 4);
  int* slotmap = (int*)alloc((size_t)NTOK * 4 * 4);
  // aliases into GUb, valid AFTER the routed gate/up GEMM consumed the weights:
  u16* Y = GUb;                                                   // 64 MB routed down out (list order)
  u16* gs_out = GUb + (size_t)NTOK * 4 * HDIM;                    // 32 MB shared gate|up, act in-place
  u16* SY = gs_out + (size_t)NTOK * 2 * FSH;                      // 16 MB shared down out

  // fp32 -> bf16 conversions
  cvt_bf16<<<8192, 256, 0, stream>>>(hidden, Xb, (long)NTOK * HDIM / 4);
  cvt_pair_moe<<<dim3(2048, 1, NEXP), 256, 0, stream>>>(gate_w, up_w, GUb);
  cvt_bf16<<<32768, 256, 0, stream>>>(down_w, Db, (long)NEXP * HDIM * FMOE / 4);
  cvt_bf16<<<4096, 256, 0, stream>>>(shg, SGUb, (long)FSH * HDIM / 4);
  cvt_bf16<<<4096, 256, 0, stream>>>(shu, SGUb + (size_t)FSH * HDIM, (long)FSH * HDIM / 4);
  cvt_bf16<<<4096, 256, 0, stream>>>(shd, SDb, (long)HDIM * FSH / 4);

  // routing + expert lists
  hipMemsetAsync(counts, 0, 64, stream);
  routing_kernel<<<NTOK / 4, 256, 0, stream>>>(hidden, gate_weight, bias, topki, topkw, counts);
  prefix16<<<1, 64, 0, stream>>>(counts, offs);
  fill_lists<<<NEXP, 256, 0, stream>>>(topki, offs, ltok, slotmap);

  // routed fused gate+up GEMM: [rows x 2048] = X(gathered) @ GU[e]^T, then in-place silu
  gemm_bt<<<dim3(2 * FMOE / 128, 32, NEXP), 256, 0, stream>>>(
      Xb, GUb, gu_out, ltok, offs, 0, 2 * FMOE, HDIM, HDIM, (long)2 * FMOE * HDIM);
  silu_mul_pair<FMOE><<<16384, 256, 0, stream>>>(gu_out, offs + NEXP, 0);
  // routed down: [rows x 2048] = act @ D[e]^T, bf16 store in list order (into old GUb region)
  gemm_bt<<<dim3(HDIM / 128, 32, NEXP), 256, 0, stream>>>(
      gu_out, Db, Y, nullptr, offs, 0, HDIM, FMOE, 2 * FMOE, (long)HDIM * FMOE);

  // shared expert: fused gate+up, silu, down
  gemm_bt<<<dim3(2 * FSH / 128, NTOK / 128, 1), 256, 0, stream>>>(
      Xb, SGUb, gs_out, nullptr, nullptr, NTOK, 2 * FSH, HDIM, HDIM, 0);
  silu_mul_pair<FSH><<<8192, 256, 0, stream>>>(gs_out, nullptr, NTOK);
  gemm_bt<<<dim3(HDIM / 128, NTOK / 128, 1), 256, 0, stream>>>(
      gs_out, SDb, SY, nullptr, nullptr, NTOK, HDIM, FSH, 2 * FSH, 0);

  // final: out[t] = SY[t] + sum_k w * Y[slot]
  reduce_out<<<8192, 256, 0, stream>>>(SY, Y, slotmap, topkw, out);
}